// Round 13
// baseline (24.046 us; speedup 1.0000x reference)
//
#include <hip/hip_runtime.h>

// Sequential implicit-midpoint solve: y_k = y_{k-1} + DT*f_k - DT*tanh(W s_k),
// s_k = (y_k + y_{k-1})/2, one wave per batch element.
//
// R13: 5-chain speculative round advancing 4 steps, with PREVIEW chain.
//   chains 0..3: midpoints of steps k..k+3, predicted with carried tanh tcar
//   chain 4:     PREVIEW midpoint of step k+4 -> tanh becomes next round's
//                tcar (carry staleness ~0.3 steps instead of 1..4).
// Corrections use the exact recurrence (fresh tanh per step), so speculation
// error enters only through tanh arguments. Calibrated error model
// (R8/R12 data, staleness^4): predicted absmax ~0.034 < 0.0506 threshold.
// 64 steps = exactly 16 rounds (no tail).
//
// Round mechanics (R10/R12-proven):
//   - pack 2 chains per lane-parity as half2 (DPP quad_perm + cvt_pkrtz):
//     region I (dwords 0..127): dword 4m+c = chain c pair m (c=0..3);
//     region II (dwords 128..159): chain-4 pair m at 128+m; odd lanes write
//     the identical value to scrap (160..191) to stay branchless. All writes
//     2 lanes/bank = free.
//   - compiler fences (memory clobber + sched_barrier(0)) keep the staged
//     broadcast ds_read_b128 AFTER the ds_write (R9 failure mode).
//   - consume: 160 v_dot2_f32_f16, 20 accumulator chains.
// W pre-scaled by 2*log2(e): tanh(Ws) = 1 - 2/(exp2(u)+1).

#define SDIM 64
#define DT_C 0.05f
#define WSCALE 2.8853900817779268f  // 2*log2(e)

typedef _Float16 h2 __attribute__((ext_vector_type(2)));  // fdot2 operand type
typedef __fp16   g2 __attribute__((ext_vector_type(2)));  // cvt_pkrtz return type
union H2U { int i; h2 h; g2 g; };

__device__ __forceinline__ float recip_fast(float x) {
    float r;
    asm("v_rcp_f32 %0, %1" : "=v"(r) : "v"(x));
    return r;
}

__device__ __forceinline__ float exp2_fast(float x) {
    float r;
    asm("v_exp_f32 %0, %1" : "=v"(r) : "v"(x));
    return r;
}

__device__ __forceinline__ h2 pack_h2(float a, float b) {
    H2U u; u.g = __builtin_amdgcn_cvt_pkrtz(a, b); return u.h;
}
__device__ __forceinline__ h2 int_as_h2(int v) {
    H2U u; u.i = v; return u.h;
}
__device__ __forceinline__ int h2_as_int(h2 v) {
    H2U u; u.h = v; return u.i;
}

__device__ __forceinline__ int dpp_nb(float s) {
    // quad_perm [1,0,3,2]: even lane gets lane+1's value, odd lane lane-1's
    return __builtin_amdgcn_update_dpp(0, __float_as_int(s), 0xB1, 0xF, 0xF, true);
}

// One 5-chain matvec round: u_c = (W s_c)_lane for c=0..4, one LDS trip.
__device__ __forceinline__ void matvec5_lds(int* lds,
                                            const h2* __restrict__ wp,
                                            int l,
                                            float s0, float s1, float s2,
                                            float s3, float s4,
                                            float& u0, float& u1, float& u2,
                                            float& u3, float& u4)
{
    const int nb0 = dpp_nb(s0);
    const int nb1 = dpp_nb(s1);
    const int nb2 = dpp_nb(s2);
    const int nb3 = dpp_nb(s3);
    const int nb4 = dpp_nb(s4);
    // even lane 2m: (s[2m], s[2m+1]); odd lane 2m+1: swap-pack = same pair
    const int pk0  = h2_as_int(pack_h2(s0, __int_as_float(nb0)));
    const int pk1  = h2_as_int(pack_h2(s1, __int_as_float(nb1)));
    const int pk2s = h2_as_int(pack_h2(__int_as_float(nb2), s2));
    const int pk3s = h2_as_int(pack_h2(__int_as_float(nb3), s3));
    const bool odd = (l & 1);
    const int pk4x = odd ? h2_as_int(pack_h2(__int_as_float(nb4), s4))
                         : h2_as_int(pack_h2(s4, __int_as_float(nb4)));

    // region I: dword 4m+c, c=0..3 (even lane writes c=0,1; odd c=2,3)
    const int w0 = odd ? pk2s : pk0;
    const int w1 = odd ? pk3s : pk1;
    reinterpret_cast<int2*>(lds)[l] = make_int2(w0, w1);
    // region II: chain-4 pair m at 128+m (even); odd writes same value to scrap
    lds[128 + (l >> 1) + (odd ? 32 : 0)] = pk4x;

    // ---- ordering fence: writes must precede the staged reads (R9 lesson) ----
    asm volatile("" ::: "memory");
    __builtin_amdgcn_sched_barrier(0);

    // stage region I: 32 broadcast b128; q[m] = (c0_m, c1_m, c2_m, c3_m)
    const int4* q4 = reinterpret_cast<const int4*>(lds);
    int4 q[32];
    #pragma unroll
    for (int m = 0; m < 32; ++m) q[m] = q4[m];
    // stage region II: 8 broadcast b128; r[i] = chain4 pairs 4i..4i+3
    int4 rr[8];
    #pragma unroll
    for (int i = 0; i < 8; ++i) rr[i] = q4[32 + i];

    float a0[4] = {0.f, 0.f, 0.f, 0.f};
    float a1[4] = {0.f, 0.f, 0.f, 0.f};
    float a2[4] = {0.f, 0.f, 0.f, 0.f};
    float a3[4] = {0.f, 0.f, 0.f, 0.f};
    float a4[4] = {0.f, 0.f, 0.f, 0.f};
    #pragma unroll
    for (int m = 0; m < 32; ++m) {
        const int4 qq = q[m];
        const h2 wm = wp[m];
        a0[m & 3] = __builtin_amdgcn_fdot2(wm, int_as_h2(qq.x), a0[m & 3], false);
        a1[m & 3] = __builtin_amdgcn_fdot2(wm, int_as_h2(qq.y), a1[m & 3], false);
        a2[m & 3] = __builtin_amdgcn_fdot2(wm, int_as_h2(qq.z), a2[m & 3], false);
        a3[m & 3] = __builtin_amdgcn_fdot2(wm, int_as_h2(qq.w), a3[m & 3], false);
    }
    #pragma unroll
    for (int i = 0; i < 8; ++i) {
        const int4 rq = rr[i];
        a4[0] = __builtin_amdgcn_fdot2(wp[4 * i + 0], int_as_h2(rq.x), a4[0], false);
        a4[1] = __builtin_amdgcn_fdot2(wp[4 * i + 1], int_as_h2(rq.y), a4[1], false);
        a4[2] = __builtin_amdgcn_fdot2(wp[4 * i + 2], int_as_h2(rq.z), a4[2], false);
        a4[3] = __builtin_amdgcn_fdot2(wp[4 * i + 3], int_as_h2(rq.w), a4[3], false);
    }
    u0 = (a0[0] + a0[1]) + (a0[2] + a0[3]);
    u1 = (a1[0] + a1[1]) + (a1[2] + a1[3]);
    u2 = (a2[0] + a2[1]) + (a2[2] + a2[3]);
    u3 = (a3[0] + a3[1]) + (a3[2] + a3[3]);
    u4 = (a4[0] + a4[1]) + (a4[2] + a4[3]);
}

__global__ __launch_bounds__(64) void rnes_seq_kernel(
    const float* __restrict__ y0,
    const float* __restrict__ forces,
    const float* __restrict__ W,
    float* __restrict__ out,
    int n, int B)
{
    const int b = blockIdx.x;
    const int l = threadIdx.x;  // lane = state component

    // W row l -> 32 half2, pre-scaled by 2*log2(e)
    h2 wp[SDIM / 2];
    {
        const float4* Wrow = reinterpret_cast<const float4*>(W + l * SDIM);
        #pragma unroll
        for (int j4 = 0; j4 < SDIM / 4; ++j4) {
            float4 v = Wrow[j4];
            wp[2 * j4 + 0] = pack_h2(WSCALE * v.x, WSCALE * v.y);
            wp[2 * j4 + 1] = pack_h2(WSCALE * v.z, WSCALE * v.w);
        }
    }

    __shared__ __align__(16) int lds[3 * SDIM];  // 192 dwords = 768 B

    const size_t stride = (size_t)B * SDIM;
    const int off = b * SDIM + l;

    float yprev = y0[off];
    out[off] = yprev;  // out[0] = y0 pass-through

    // Seed tanh carry at s ~= y0 (all chains replicated; take u0)
    float u0, u1, u2, u3, u4, tcar;
    matvec5_lds(lds, wp, l, yprev, yprev, yprev, yprev, yprev, u0, u1, u2, u3, u4);
    tcar = fmaf(-2.0f, recip_fast(exp2_fast(u0) + 1.0f), 1.0f);

    // force ring fR0..fR4 = f_k..f_{k+4}
    float fR0 = (n > 1) ? forces[1 * stride + off] : 0.f;
    float fR1 = (n > 2) ? forces[2 * stride + off] : 0.f;
    float fR2 = (n > 3) ? forces[3 * stride + off] : 0.f;
    float fR3 = (n > 4) ? forces[4 * stride + off] : 0.f;
    float fR4 = (n > 5) ? forces[5 * stride + off] : 0.f;
    const float* fpre = forces + 6 * stride + off;  // next to load: f_{k+5}
    float* op = out + stride + off;

    int k = 1;
    #pragma unroll 1
    for (; k + 3 < n; k += 4) {
        // prefetch next round's f_{k+5}..f_{k+8} (a full round of slack)
        float pf0 = 0.f, pf1 = 0.f, pf2 = 0.f, pf3 = 0.f;
        if (k + 5 < n) pf0 = fpre[0 * stride];
        if (k + 6 < n) pf1 = fpre[1 * stride];
        if (k + 7 < n) pf2 = fpre[2 * stride];
        if (k + 8 < n) pf3 = fpre[3 * stride];
        fpre += 4 * stride;

        // speculative midpoints with carried tanh (preview-fresh, stale ~0.3)
        const float d0 = fR0 - tcar;
        const float s0 = fmaf(0.5f * DT_C, d0, yprev);
        const float yp0 = fmaf(DT_C, d0, yprev);
        const float d1 = fR1 - tcar;
        const float s1 = fmaf(0.5f * DT_C, d1, yp0);
        const float yp1 = fmaf(DT_C, d1, yp0);
        const float d2 = fR2 - tcar;
        const float s2 = fmaf(0.5f * DT_C, d2, yp1);
        const float yp2 = fmaf(DT_C, d2, yp1);
        const float d3 = fR3 - tcar;
        const float s3 = fmaf(0.5f * DT_C, d3, yp2);
        const float yp3 = fmaf(DT_C, d3, yp2);
        const float d4 = fR4 - tcar;
        const float s4 = fmaf(0.5f * DT_C, d4, yp3);   // PREVIEW midpoint k+4

        matvec5_lds(lds, wp, l, s0, s1, s2, s3, s4, u0, u1, u2, u3, u4);

        const float r0 = recip_fast(exp2_fast(u0) + 1.0f);
        const float r1 = recip_fast(exp2_fast(u1) + 1.0f);
        const float r2 = recip_fast(exp2_fast(u2) + 1.0f);
        const float r3 = recip_fast(exp2_fast(u3) + 1.0f);
        const float r4 = recip_fast(exp2_fast(u4) + 1.0f);

        // exact-recurrence corrections with fresh tanh
        const float y1c = fmaf(2.0f * DT_C, r0, fmaf(DT_C, fR0, yprev) - DT_C);
        const float y2c = fmaf(2.0f * DT_C, r1, fmaf(DT_C, fR1, y1c) - DT_C);
        const float y3c = fmaf(2.0f * DT_C, r2, fmaf(DT_C, fR2, y2c) - DT_C);
        const float y4c = fmaf(2.0f * DT_C, r3, fmaf(DT_C, fR3, y3c) - DT_C);

        op[0 * stride] = y1c;
        op[1 * stride] = y2c;
        op[2 * stride] = y3c;
        op[3 * stride] = y4c;
        op += 4 * stride;

        yprev = y4c;
        tcar = fmaf(-2.0f, r4, 1.0f);  // preview tanh -> next round's carry
        fR0 = fR4; fR1 = pf0; fR2 = pf1; fR3 = pf2; fR4 = pf3;
    }

    // generic 1-step tail (not hit for n=65)
    #pragma unroll 1
    for (; k < n; ++k) {
        const float s = fmaf(0.5f * DT_C, fR0 - tcar, yprev);
        matvec5_lds(lds, wp, l, s, s, s, s, s, u0, u1, u2, u3, u4);
        const float r = recip_fast(exp2_fast(u0) + 1.0f);
        const float y = fmaf(2.0f * DT_C, r, fmaf(DT_C, fR0, yprev) - DT_C);
        *op = y;
        op += stride;
        yprev = y;
        tcar = fmaf(-2.0f, r, 1.0f);
        fR0 = fR1; fR1 = fR2; fR2 = fR3; fR3 = fR4;
    }
}

extern "C" void kernel_launch(void* const* d_in, const int* in_sizes, int n_in,
                              void* d_out, int out_size, void* d_ws, size_t ws_size,
                              hipStream_t stream) {
    const float* y0     = (const float*)d_in[0];   // (B, S)
    const float* forces = (const float*)d_in[1];   // (n, B, S)
    const float* W      = (const float*)d_in[2];   // (S, S)
    float* out = (float*)d_out;                    // (n, B, S)

    const int BS = in_sizes[0];       // B * S
    const int B  = BS / SDIM;         // 128
    const int n  = in_sizes[1] / BS;  // 65

    rnes_seq_kernel<<<B, SDIM, 0, stream>>>(y0, forces, W, out, n, B);
}

// Round 15
// 17.421 us; speedup vs baseline: 1.3803x; 1.3803x over previous
//
#include <hip/hip_runtime.h>

// Sequential implicit-midpoint solve: y_k = y_{k-1} + DT*f_k - DT*tanh(W s_k),
// s_k = (y_k + y_{k-1})/2, one wave per batch element.
//
// R15 = R14 with the compile fix: MFMA macro gated on __HIP_DEVICE_COMPILE__
// (R14's __has_builtin gate failed the HOST pass) and the canonical builtin
// name __builtin_amdgcn_mfma_f32_16x16x16f16.
//
// Structure: R13's 5-chain round (4 steps + preview chain, known-passing
// numerics, absmax 0.0434) with the matvec consume on MATRIX CORES:
//   D[16x64] = S^T (A: rows = chains 0..4, rest ignored) @ W^T (B)
//   = 4 output tiles x (K=64/16) = 16x mfma_f32_16x16x16f16.
// R13's regression was 160 staged VGPRs + 160 serial fdot2; here staged data
// is 4x ds_read_b64 (A-frags), W is 32 static VGPRs, consume is 16 MFMAs.
//
// Layouts (canonical CDNA 16x16x16 f16):
//   A: lane holds A[l&15][4*(l>>4)+kk]           -> chain l&15, 4 comps
//   B: lane holds B[4*(l>>4)+kk][l&15]           -> W[16t+(l&15)][16h+4*(l>>4)+kk]
//   D: lane holds D[4*(l>>4)+j][l&15]            -> lanes 0..15 = chains 0..3,
//                                                   lanes 16..31 reg0 = chain 4
// Redistribution via LDS (single wave, in-order DS pipe + fences, R10-proven).
// W pre-scaled by 2*log2(e): tanh(Ws) = 1 - 2/(exp2(u)+1).

#define SDIM 64
#define DT_C 0.05f
#define WSCALE 2.8853900817779268f  // 2*log2(e)
#define SPITCH 36                   // dword pitch per chain region (bank stagger)

typedef _Float16 v4h __attribute__((ext_vector_type(4)));
typedef float    v4f __attribute__((ext_vector_type(4)));
typedef __fp16   g2  __attribute__((ext_vector_type(2)));

#if defined(__HIP_DEVICE_COMPILE__)
#define MFMA16(A, B, C) __builtin_amdgcn_mfma_f32_16x16x16f16((A), (B), (C), 0, 0, 0)
#else
// host pass only parses device code; never executed
#define MFMA16(A, B, C) ((void)(A), (void)(B), (C))
#endif

union H2U  { int i;  g2 g; };
union V4HU { int2 i2; v4h h; g2 g[2]; };

__device__ __forceinline__ float recip_fast(float x) {
    float r; asm("v_rcp_f32 %0, %1" : "=v"(r) : "v"(x)); return r;
}
__device__ __forceinline__ float exp2_fast(float x) {
    float r; asm("v_exp_f32 %0, %1" : "=v"(r) : "v"(x)); return r;
}
__device__ __forceinline__ int pack_h2i(float a, float b) {
    H2U u; u.g = __builtin_amdgcn_cvt_pkrtz(a, b); return u.i;
}
__device__ __forceinline__ v4h pack_h4(float a, float b, float c, float d) {
    V4HU u;
    u.g[0] = __builtin_amdgcn_cvt_pkrtz(a, b);
    u.g[1] = __builtin_amdgcn_cvt_pkrtz(c, d);
    return u.h;
}
__device__ __forceinline__ v4h i2_as_h4(int2 v) { V4HU u; u.i2 = v; return u.h; }
__device__ __forceinline__ int dpp_nb(float s) {
    // quad_perm [1,0,3,2]: even lane gets lane+1's value, odd lane lane-1's
    return __builtin_amdgcn_update_dpp(0, __float_as_int(s), 0xB1, 0xF, 0xF, true);
}

// 5-chain matvec round via MFMA: u_c = (W s_c)_lane, c=0..4.
__device__ __forceinline__ void matvec5_mfma(int* lds_s, float* lds_u,
                                             const v4h* __restrict__ wb,
                                             int l,
                                             float s0, float s1, float s2,
                                             float s3, float s4,
                                             float& u0, float& u1, float& u2,
                                             float& u3, float& u4)
{
    const bool odd = (l & 1);
    const int m = l >> 1;

    // packed pair (s_c[2m], s_c[2m+1]) per chain (parity-dependent pack order)
    const float n0 = __int_as_float(dpp_nb(s0));
    const float n1 = __int_as_float(dpp_nb(s1));
    const float n2 = __int_as_float(dpp_nb(s2));
    const float n3 = __int_as_float(dpp_nb(s3));
    const float n4 = __int_as_float(dpp_nb(s4));
    const int p0 = odd ? pack_h2i(n0, s0) : pack_h2i(s0, n0);
    const int p1 = odd ? pack_h2i(n1, s1) : pack_h2i(s1, n1);
    const int p2 = odd ? pack_h2i(n2, s2) : pack_h2i(s2, n2);
    const int p3 = odd ? pack_h2i(n3, s3) : pack_h2i(s3, n3);
    const int p4 = odd ? pack_h2i(n4, s4) : pack_h2i(s4, n4);

    // chain-major layout: dword c*SPITCH + m = h2(s_c[2m], s_c[2m+1])
    if (!odd) {
        lds_s[0 * SPITCH + m] = p0;
        lds_s[1 * SPITCH + m] = p1;
        lds_s[4 * SPITCH + m] = p4;
    } else {
        lds_s[2 * SPITCH + m] = p2;
        lds_s[3 * SPITCH + m] = p3;
    }

    // ---- fence: writes precede the A-frag reads (R9 lesson) ----
    asm volatile("" ::: "memory");
    __builtin_amdgcn_sched_barrier(0);

    // A-frags: chain c = l&15, comps 16h + 4*(l>>4)..+3 -> ds_read_b64 each
    const int2* s2p = reinterpret_cast<const int2*>(lds_s);
    const int abase = 18 * (l & 15) + (l >> 4);   // int2 units (SPITCH/2 = 18)
    const v4h a0 = i2_as_h4(s2p[abase + 0]);
    const v4h a1 = i2_as_h4(s2p[abase + 4]);
    const v4h a2 = i2_as_h4(s2p[abase + 8]);
    const v4h a3 = i2_as_h4(s2p[abase + 12]);

    // 16 MFMAs: tile t (output comps 16t..16t+15) x K-chunks h=0..3
    v4f c0 = {0.f, 0.f, 0.f, 0.f};
    v4f c1 = c0, c2 = c0, c3 = c0;
    c0 = MFMA16(a0, wb[0],  c0);  c1 = MFMA16(a0, wb[4],  c1);
    c2 = MFMA16(a0, wb[8],  c2);  c3 = MFMA16(a0, wb[12], c3);
    c0 = MFMA16(a1, wb[1],  c0);  c1 = MFMA16(a1, wb[5],  c1);
    c2 = MFMA16(a1, wb[9],  c2);  c3 = MFMA16(a1, wb[13], c3);
    c0 = MFMA16(a2, wb[2],  c0);  c1 = MFMA16(a2, wb[6],  c1);
    c2 = MFMA16(a2, wb[10], c2);  c3 = MFMA16(a2, wb[14], c3);
    c0 = MFMA16(a3, wb[3],  c0);  c1 = MFMA16(a3, wb[7],  c1);
    c2 = MFMA16(a3, wb[11], c2);  c3 = MFMA16(a3, wb[15], c3);

    // redistribution: lanes 0..15 hold chains 0..3 of comp 16t+l in c_t regs;
    // lanes 16..31 hold chain 4 of comp 16t+(l&15) in c_t reg 0.
    if (l < 16) {
        float4* up = reinterpret_cast<float4*>(lds_u);
        up[0 * 16 + l] = make_float4(c0.x, c0.y, c0.z, c0.w);
        up[1 * 16 + l] = make_float4(c1.x, c1.y, c1.z, c1.w);
        up[2 * 16 + l] = make_float4(c2.x, c2.y, c2.z, c2.w);
        up[3 * 16 + l] = make_float4(c3.x, c3.y, c3.z, c3.w);
    } else if (l < 32) {
        const int q = l & 15;
        lds_u[256 + 0 * 16 + q] = c0.x;
        lds_u[256 + 1 * 16 + q] = c1.x;
        lds_u[256 + 2 * 16 + q] = c2.x;
        lds_u[256 + 3 * 16 + q] = c3.x;
    }

    asm volatile("" ::: "memory");
    __builtin_amdgcn_sched_barrier(0);

    const float4 uq = reinterpret_cast<const float4*>(lds_u)[l];
    u0 = uq.x; u1 = uq.y; u2 = uq.z; u3 = uq.w;
    u4 = lds_u[256 + l];
}

__global__ __launch_bounds__(64) void rnes_seq_kernel(
    const float* __restrict__ y0,
    const float* __restrict__ forces,
    const float* __restrict__ W,
    float* __restrict__ out,
    int n, int B)
{
    const int b = blockIdx.x;
    const int l = threadIdx.x;  // lane = state component

    // B-operand frags: wb[t*4+h] = W[16t+(l&15)][16h+4*(l>>4)+kk], scaled
    v4h wb[16];
    {
        const int co = l & 15, g = l >> 4;
        #pragma unroll
        for (int t = 0; t < 4; ++t) {
            #pragma unroll
            for (int h = 0; h < 4; ++h) {
                const float4 v = *reinterpret_cast<const float4*>(
                    W + (16 * t + co) * 64 + 16 * h + 4 * g);
                wb[t * 4 + h] = pack_h4(WSCALE * v.x, WSCALE * v.y,
                                        WSCALE * v.z, WSCALE * v.w);
            }
        }
    }

    __shared__ __align__(16) int   lds_s[576];  // 16*SPITCH dwords
    __shared__ __align__(16) float lds_u[320];

    // zero lds_s once: A rows 5..15 then read zeros (deterministic, no NaNs)
    #pragma unroll
    for (int i = 0; i < 9; ++i) lds_s[i * 64 + l] = 0;

    const size_t stride = (size_t)B * SDIM;
    const int off = b * SDIM + l;

    float yprev = y0[off];
    out[off] = yprev;  // out[0] = y0 pass-through

    // Seed tanh carry at s ~= y0
    float u0, u1, u2, u3, u4, tcar;
    matvec5_mfma(lds_s, lds_u, wb, l, yprev, yprev, yprev, yprev, yprev,
                 u0, u1, u2, u3, u4);
    tcar = fmaf(-2.0f, recip_fast(exp2_fast(u0) + 1.0f), 1.0f);

    // force ring fR0..fR4 = f_k..f_{k+4}
    float fR0 = (n > 1) ? forces[1 * stride + off] : 0.f;
    float fR1 = (n > 2) ? forces[2 * stride + off] : 0.f;
    float fR2 = (n > 3) ? forces[3 * stride + off] : 0.f;
    float fR3 = (n > 4) ? forces[4 * stride + off] : 0.f;
    float fR4 = (n > 5) ? forces[5 * stride + off] : 0.f;
    const float* fpre = forces + 6 * stride + off;
    float* op = out + stride + off;

    int k = 1;
    #pragma unroll 1
    for (; k + 3 < n; k += 4) {
        float pf0 = 0.f, pf1 = 0.f, pf2 = 0.f, pf3 = 0.f;
        if (k + 5 < n) pf0 = fpre[0 * stride];
        if (k + 6 < n) pf1 = fpre[1 * stride];
        if (k + 7 < n) pf2 = fpre[2 * stride];
        if (k + 8 < n) pf3 = fpre[3 * stride];
        fpre += 4 * stride;

        // speculative midpoints with carried tanh (R13 numerics, verbatim)
        const float d0 = fR0 - tcar;
        const float s0 = fmaf(0.5f * DT_C, d0, yprev);
        const float yp0 = fmaf(DT_C, d0, yprev);
        const float d1 = fR1 - tcar;
        const float s1 = fmaf(0.5f * DT_C, d1, yp0);
        const float yp1 = fmaf(DT_C, d1, yp0);
        const float d2 = fR2 - tcar;
        const float s2 = fmaf(0.5f * DT_C, d2, yp1);
        const float yp2 = fmaf(DT_C, d2, yp1);
        const float d3 = fR3 - tcar;
        const float s3 = fmaf(0.5f * DT_C, d3, yp2);
        const float yp3 = fmaf(DT_C, d3, yp2);
        const float d4 = fR4 - tcar;
        const float s4 = fmaf(0.5f * DT_C, d4, yp3);  // PREVIEW midpoint k+4

        matvec5_mfma(lds_s, lds_u, wb, l, s0, s1, s2, s3, s4,
                     u0, u1, u2, u3, u4);

        const float r0 = recip_fast(exp2_fast(u0) + 1.0f);
        const float r1 = recip_fast(exp2_fast(u1) + 1.0f);
        const float r2 = recip_fast(exp2_fast(u2) + 1.0f);
        const float r3 = recip_fast(exp2_fast(u3) + 1.0f);
        const float r4 = recip_fast(exp2_fast(u4) + 1.0f);

        // exact-recurrence corrections with fresh tanh
        const float y1c = fmaf(2.0f * DT_C, r0, fmaf(DT_C, fR0, yprev) - DT_C);
        const float y2c = fmaf(2.0f * DT_C, r1, fmaf(DT_C, fR1, y1c) - DT_C);
        const float y3c = fmaf(2.0f * DT_C, r2, fmaf(DT_C, fR2, y2c) - DT_C);
        const float y4c = fmaf(2.0f * DT_C, r3, fmaf(DT_C, fR3, y3c) - DT_C);

        op[0 * stride] = y1c;
        op[1 * stride] = y2c;
        op[2 * stride] = y3c;
        op[3 * stride] = y4c;
        op += 4 * stride;

        yprev = y4c;
        tcar = fmaf(-2.0f, r4, 1.0f);  // preview tanh -> next round's carry
        fR0 = fR4; fR1 = pf0; fR2 = pf1; fR3 = pf2; fR4 = pf3;
    }

    // generic 1-step tail (not hit for n=65)
    #pragma unroll 1
    for (; k < n; ++k) {
        const float s = fmaf(0.5f * DT_C, fR0 - tcar, yprev);
        matvec5_mfma(lds_s, lds_u, wb, l, s, s, s, s, s, u0, u1, u2, u3, u4);
        const float r = recip_fast(exp2_fast(u0) + 1.0f);
        const float y = fmaf(2.0f * DT_C, r, fmaf(DT_C, fR0, yprev) - DT_C);
        *op = y;
        op += stride;
        yprev = y;
        tcar = fmaf(-2.0f, r, 1.0f);
        fR0 = fR1; fR1 = fR2; fR2 = fR3; fR3 = fR4;
    }
}

extern "C" void kernel_launch(void* const* d_in, const int* in_sizes, int n_in,
                              void* d_out, int out_size, void* d_ws, size_t ws_size,
                              hipStream_t stream) {
    const float* y0     = (const float*)d_in[0];   // (B, S)
    const float* forces = (const float*)d_in[1];   // (n, B, S)
    const float* W      = (const float*)d_in[2];   // (S, S)
    float* out = (float*)d_out;                    // (n, B, S)

    const int BS = in_sizes[0];       // B * S
    const int B  = BS / SDIM;         // 128
    const int n  = in_sizes[1] / BS;  // 65

    rnes_seq_kernel<<<B, SDIM, 0, stream>>>(y0, forces, W, out, n, B);
}